// Round 6
// baseline (268.563 us; speedup 1.0000x reference)
//
#include <hip/hip_runtime.h>
#include <math.h>

#define NPTS 200001

typedef _Float16 f16;
typedef f16 f16x2 __attribute__((ext_vector_type(2)));
typedef f16 f16x8 __attribute__((ext_vector_type(8)));
typedef float f32x16 __attribute__((ext_vector_type(16)));

// ---------------------------------------------------------------------------
// Packed B region (workspace AND LDS image), 24,128 B total:
//   B1: [28 ksteps][49 units][8 f16]  unit = hf*24+col (col<24), unit 48 = zeros
//   B2: [ 8 ksteps][17 units][8 f16]  unit = hf*8+w    (w<8),    unit 16 = zeros
// Combined accumulators: accA = path1 (cols 0..15 scal, 16..23 gates) +
// path2 i=0 (cols 24..31); accB = i=1 (cols 0..7) + i=2 (cols 8..15).
// v6: v4 epilogue/math byte-identical; block size 256 -> 1024 threads so the
// 24.1KB B-image is shared by 16 waves: LDS/block = 65,088 B -> 2 blocks/CU
// -> 32 waves/CU at the ~64-VGPR budget the compiler naturally picks
// (v3/v4/v5 all chose 60-64). Doubles memory concurrency; no prefetch, no
// long live ranges for the allocator to spill (v2/v5 lesson).
// ---------------------------------------------------------------------------
#define B1BYTES  21952
#define B2OFF    21952
#define BBYTES   24128
#define STAGEOFF 24128                    // + wid*2560 : per-wave 16 rows x 40 f
#define LDSBYTES (24128 + 16*2560)        // 65,088 B -> 2 blocks/CU

__global__ void prep(const float* __restrict__ wss0, const float* __restrict__ wvv0,
                     const float* __restrict__ wss1, const float* __restrict__ wvv1,
                     const float* __restrict__ wsv,  const float* __restrict__ wvs,
                     float* __restrict__ partials, f16* __restrict__ bpack)
{
    const int b = blockIdx.x;
    const int t = threadIdx.x;
    if (b < 4) {
        float ls = 0.f, lg = 0.f;
        for (int i = b * 256 + t; i < NPTS; i += 1024) {
            float xv  = -12.0f + 24.0f * ((float)i / 200000.0f);
            float pdf = __expf(-0.5f * xv * xv) * 0.39894228040143267794f;
            float sg  = 1.0f / (1.0f + __expf(-xv));
            float si  = xv * sg;
            float wt  = (i == 0 || i == NPTS - 1) ? 0.5f : 1.0f;
            ls = fmaf(wt * si * si, pdf, ls);
            lg = fmaf(wt * sg * sg, pdf, lg);
        }
        __shared__ float r1[256], r2[256];
        r1[t] = ls; r2[t] = lg;
        __syncthreads();
        for (int st = 128; st > 0; st >>= 1) {
            if (t < st) { r1[t] += r1[t + st]; r2[t] += r2[t + st]; }
            __syncthreads();
        }
        if (t == 0) { partials[b] = r1[0]; partials[4 + b] = r2[0]; }
    } else {
        const int gid = (b - 4) * 256 + t;
        const float CSC  = 0.05590169943749474241f;                       // 1/sqrt(320)
        const float CSC3 = 0.05590169943749474241f / 1.7320508075688772935f;
        if (gid < 10976) {                       // B1: [28][49][8]
            const int tk   = gid / 392;          // 49*8
            const int rem  = gid - tk * 392;
            const int unit = rem >> 3;
            const int j    = rem & 7;
            float val = 0.f;
            if (unit < 48) {
                const int hf  = (unit >= 24) ? 1 : 0;
                const int col = unit - 24 * hf;
                const int k   = tk * 16 + hf * 8 + j;
                if (k < 256) {
                    const int u = k >> 4, t16 = k & 15;
                    val = (col < 16) ? CSC * wss0[(u * 16 + t16) * 16 + col]
                                     : CSC * wss1[(u * 16 + t16) * 8 + (col - 16)];
                } else {
                    const int kk = k - 256;
                    const int r8 = (kk >> 3) & 7, c8 = kk & 7;
                    val = (col < 16) ? CSC3 * wvv0[(r8 * 8 + c8) * 16 + col]
                                     : CSC3 * wvv1[(r8 * 8 + c8) * 8 + (col - 16)];
                }
            }
            bpack[gid] = (f16)val;
        } else if (gid < 12064) {                // B2: [8][17][8]
            const int e    = gid - 10976;
            const int ks   = e / 136;            // 17*8
            const int rem  = e - ks * 136;
            const int unit = rem >> 3;
            const int j    = rem & 7;
            float val = 0.f;
            if (unit < 16) {
                const int hf = unit >> 3;
                const int w  = unit & 7;
                const int k  = ks * 16 + hf * 8 + j;
                const int a  = k >> 3, bb = k & 7;
                val = 0.0625f * (wsv[(a * 8 + bb) * 8 + w] + wvs[(bb * 16 + a) * 8 + w]);
            }
            bpack[gid] = (f16)val;
        }
    }
}

// ---------------------------------------------------------------------------
// Main kernel v6: v4 body, 1024-thread blocks (16 waves share one B-image).
// C-layout: col = lane&31, row = (reg&3)+8*(reg>>2)+4*(lane>>5).
// ---------------------------------------------------------------------------
__global__ __launch_bounds__(1024, 8) void seg_main(
    const float* __restrict__ x,
    const f16* __restrict__ bpack,    // 24,128 B packed B1+B2
    const float* __restrict__ partials,
    float* __restrict__ out, int n, int nchunks)
{
    const int tid  = threadIdx.x;
    const int lane = tid & 63;
    const int wid  = tid >> 6;        // 0..15
    const int col  = lane & 31;
    const int hf   = lane >> 5;

    __shared__ float4 lds4[LDSBYTES / 16];
    {
        const float4* src = (const float4*)bpack;
#pragma unroll
        for (int i = 0; i < 2; ++i) {
            const int idx = i * 1024 + tid;
            if (idx < BBYTES / 16) lds4[idx] = src[idx];
        }
    }
    __syncthreads();

    char* ldsc = (char*)lds4;
    // per-lane B-fragment base byte offsets (zero unit for inactive lanes)
    const int uA = (col < 24) ? (hf * 24 + col) * 16 : 48 * 16;
    const int u0 = B2OFF + ((col >= 24) ? (hf * 8 + col - 24) * 16 : 256);
    const int u1 = B2OFF + ((col < 8)   ? (hf * 8 + col) * 16      : 256);
    const int u2 = B2OFF + ((col >= 8 && col < 16) ? (hf * 8 + col - 8) * 16 : 256);
    const f16x8* BA  = (const f16x8*)(ldsc + uA);   // index t*49  (784 B stride)
    const f16x8* B0p = (const f16x8*)(ldsc + u0);   // index ks*17 (272 B stride)
    const f16x8* B1p = (const f16x8*)(ldsc + u1);
    const f16x8* B2p = (const f16x8*)(ldsc + u2);

    float*  stagef = (float*)(ldsc + STAGEOFF + wid * 2560);
    float4* stage4 = (float4*)(ldsc + STAGEOFF + wid * 2560);

    // gate(z,w) lives at lane hf*32+16+w; every consumer group uses w = col&7
    const int gsrc = 4 * (hf * 32 + 16 + (col & 7));
    // v-out dword offset within a 40-float row: 16 + w*3 + i per lane group
    const int vo   = 16 + (col & 7) * 3 + ((col < 8) ? 1 : ((col < 16) ? 2 : 0));
    const bool wrV = (col < 16) || (col >= 24);

    const float dx = 24.0f / 200000.0f;
    const float silu_c = rsqrtf((partials[0] + partials[1] + partials[2] + partials[3]) * dx);
    const float sig_c  = rsqrtf((partials[4] + partials[5] + partials[6] + partials[7]) * dx);

    const long long nf40 = (long long)n * 40;
    const int stride = gridDim.x * 16;

    for (int chunk = blockIdx.x * 16 + wid; chunk < nchunks; chunk += stride) {
        const int row  = chunk * 32 + col;
        const int lrow = (row < n) ? row : (n - 1);

        // ---- load row as named float4s, convert immediately ----
        f16x2 s2[8];        // s2[a] = {s[2a], s[2a+1]}
        f16x2 vc[3][4];     // vc[i][m] = {v[2m][i], v[2m+1][i]}
        {
            const float4* p4 = (const float4*)(x + (size_t)lrow * 40);
            float4 q0 = p4[0], q1 = p4[1], q2 = p4[2], q3 = p4[3], q4 = p4[4];
            float4 q5 = p4[5], q6 = p4[6], q7 = p4[7], q8 = p4[8], q9 = p4[9];
            s2[0].x = (f16)q0.x; s2[0].y = (f16)q0.y;
            s2[1].x = (f16)q0.z; s2[1].y = (f16)q0.w;
            s2[2].x = (f16)q1.x; s2[2].y = (f16)q1.y;
            s2[3].x = (f16)q1.z; s2[3].y = (f16)q1.w;
            s2[4].x = (f16)q2.x; s2[4].y = (f16)q2.y;
            s2[5].x = (f16)q2.z; s2[5].y = (f16)q2.w;
            s2[6].x = (f16)q3.x; s2[6].y = (f16)q3.y;
            s2[7].x = (f16)q3.z; s2[7].y = (f16)q3.w;
            vc[0][0].x = (f16)q4.x; vc[0][0].y = (f16)q4.w;
            vc[1][0].x = (f16)q4.y; vc[1][0].y = (f16)q5.x;
            vc[2][0].x = (f16)q4.z; vc[2][0].y = (f16)q5.y;
            vc[0][1].x = (f16)q5.z; vc[0][1].y = (f16)q6.y;
            vc[1][1].x = (f16)q5.w; vc[1][1].y = (f16)q6.z;
            vc[2][1].x = (f16)q6.x; vc[2][1].y = (f16)q6.w;
            vc[0][2].x = (f16)q7.x; vc[0][2].y = (f16)q7.w;
            vc[1][2].x = (f16)q7.y; vc[1][2].y = (f16)q8.x;
            vc[2][2].x = (f16)q7.z; vc[2][2].y = (f16)q8.y;
            vc[0][3].x = (f16)q8.z; vc[0][3].y = (f16)q9.y;
            vc[1][3].x = (f16)q8.w; vc[1][3].y = (f16)q9.z;
            vc[2][3].x = (f16)q9.x; vc[2][3].y = (f16)q9.w;
        }

        f16x2 shp[4];
#pragma unroll
        for (int m = 0; m < 4; ++m) shp[m] = hf ? s2[4 + m] : s2[m];

        union { f16x2 h[4]; f16x8 v; } A;
        f32x16 accA, accB;
#pragma unroll
        for (int r = 0; r < 16; ++r) { accA[r] = 0.f; accB[r] = 0.f; }

        // ---- path1 ss: ksteps t=0..15 -> accA ----
#pragma unroll
        for (int t = 0; t < 16; ++t) {
            f16 sv = (t & 1) ? s2[t >> 1].y : s2[t >> 1].x;
            f16x2 su2; su2.x = sv; su2.y = sv;
#pragma unroll
            for (int m = 0; m < 4; ++m) A.h[m] = su2 * shp[m];
            accA = __builtin_amdgcn_mfma_f32_32x32x16_f16(A.v, BA[t * 49], accA, 0, 0, 0);
        }
        // ---- path1 vv: ksteps tt=0..11 -> accA ----
#pragma unroll
        for (int tt = 0; tt < 12; ++tt) {
            const int i   = tt >> 2;
            const int ttm = tt & 3;
            f16x2 pr = vc[i][ttm];
            f16 sv = hf ? pr.y : pr.x;
            f16x2 su2; su2.x = sv; su2.y = sv;
#pragma unroll
            for (int m = 0; m < 4; ++m) A.h[m] = su2 * vc[i][m];
            accA = __builtin_amdgcn_mfma_f32_32x32x16_f16(A.v, BA[(16 + tt) * 49], accA, 0, 0, 0);
        }
        // ---- path2: i0 -> accA cols 24..31; i1,i2 -> accB cols 0..15 ----
#pragma unroll
        for (int ks = 0; ks < 8; ++ks) {
            f16x2 pr = s2[ks];
            f16 sv = hf ? pr.y : pr.x;
            f16x2 su2; su2.x = sv; su2.y = sv;
            union { f16x2 h[4]; f16x8 v; } A0, A1, A2;
#pragma unroll
            for (int m = 0; m < 4; ++m) {
                A0.h[m] = su2 * vc[0][m];
                A1.h[m] = su2 * vc[1][m];
                A2.h[m] = su2 * vc[2][m];
            }
            accA = __builtin_amdgcn_mfma_f32_32x32x16_f16(A0.v, B0p[ks * 17], accA, 0, 0, 0);
            accB = __builtin_amdgcn_mfma_f32_32x32x16_f16(A1.v, B1p[ks * 17], accB, 0, 0, 0);
            accB = __builtin_amdgcn_mfma_f32_32x32x16_f16(A2.v, B2p[ks * 17], accB, 0, 0, 0);
        }

        // ---- epilogue: stage 16 rows in LDS, flush fully coalesced ----
#pragma unroll
        for (int half = 0; half < 2; ++half) {
#pragma unroll
            for (int rr = 0; rr < 8; ++rr) {
                const int r = half * 8 + rr;
                const float aval = accA[r];
                const float sgm  = 1.0f / (1.0f + __expf(-aval));
                const float gm   = __int_as_float(
                    __builtin_amdgcn_ds_bpermute(gsrc, __float_as_int(sig_c * sgm)));
                const int zloc = (rr & 3) + 8 * (rr >> 2) + 4 * hf;   // z - half*16
                if (col < 16) stagef[zloc * 40 + col] = silu_c * aval * sgm;
                if (wrV)      stagef[zloc * 40 + vo]  = gm * ((col < 16) ? accB[r] : aval);
            }
            // flush 16 rows = 2560 B, contiguous in out
            if (chunk * 32 + half * 16 + 15 < n) {
                float4* o4 = (float4*)out + (size_t)chunk * 320 + half * 160;
                float4 f0 = stage4[lane];
                float4 f1 = stage4[64 + lane];
                o4[lane]      = f0;
                o4[64 + lane] = f1;
                if (lane < 32) { float4 f2 = stage4[128 + lane]; o4[128 + lane] = f2; }
            } else {
#pragma unroll
                for (int k2 = 0; k2 < 3; ++k2) {
                    if (k2 == 2 && lane >= 32) break;
                    float4 fv = stage4[k2 * 64 + lane];
                    const long long fbase = (long long)chunk * 1280 + half * 640
                                          + (k2 * 64 + lane) * 4;
#pragma unroll
                    for (int e = 0; e < 4; ++e) {
                        const long long fi = fbase + e;
                        if (fi < nf40) out[fi] = ((const float*)&fv)[e];
                    }
                }
            }
        }
    }
}

// ---------------------------------------------------------------------------
extern "C" void kernel_launch(void* const* d_in, const int* in_sizes, int n_in,
                              void* d_out, int out_size, void* d_ws, size_t ws_size,
                              hipStream_t stream)
{
    (void)n_in; (void)out_size; (void)ws_size;
    const float* x    = (const float*)d_in[0];
    const float* wss0 = (const float*)d_in[1];
    const float* wvv0 = (const float*)d_in[2];
    const float* wss1 = (const float*)d_in[3];
    const float* wvv1 = (const float*)d_in[4];
    const float* wsv  = (const float*)d_in[5];
    const float* wvs  = (const float*)d_in[6];
    float* out = (float*)d_out;
    const int n = in_sizes[0] / 40;
    const int nchunks = (n + 31) / 32;

    char* ws = (char*)d_ws;
    float* partials = (float*)(ws + 0);        // 8 floats
    f16*   bpack    = (f16*)(ws + 1024);       // 24,128 B packed B1+B2

    int grid = (nchunks + 15) / 16;
    if (grid > 512) grid = 512;                // 2 blocks/CU resident

    hipLaunchKernelGGL(prep, dim3(52), dim3(256), 0, stream,
                       wss0, wvv0, wss1, wvv1, wsv, wvs, partials, bpack);
    hipLaunchKernelGGL(seg_main, dim3(grid), dim3(1024), 0, stream,
                       x, bpack, partials, out, n, nchunks);
}

// Round 7
// 193.765 us; speedup vs baseline: 1.3860x; 1.3860x over previous
//
#include <hip/hip_runtime.h>
#include <math.h>

#define NPTS 200001

typedef _Float16 f16;
typedef f16 f16x2 __attribute__((ext_vector_type(2)));
typedef f16 f16x8 __attribute__((ext_vector_type(8)));
typedef float f32x16 __attribute__((ext_vector_type(16)));

// ---------------------------------------------------------------------------
// Packed B region (workspace AND LDS image), 24,128 B total:
//   B1: [28 ksteps][49 units][8 f16]  unit = hf*24+col (col<24), unit 48 = zeros
//   B2: [ 8 ksteps][17 units][8 f16]  unit = hf*8+w    (w<8),    unit 16 = zeros
// Combined accumulators: accA = path1 (cols 0..15 scal, 16..23 gates) +
// path2 i=0 (cols 24..31); accB = i=1 (cols 0..7) + i=2 (cols 8..15).
// v7 = v6 with __launch_bounds__(1024) ONLY (no min-waves arg).
// History: v4 (256thr, cap128) -> VGPR 60, clean, 64us.
//          v6 (1024thr, waves-per-eu>=8) -> VGPR 32, scratch storm, 139us
//          (occupancy 76% proved 2 blocks/CU works; allocation broke).
// The allocator must be left at its natural ~60-64 choice; occupancy then
// follows: VGPR<=64 -> 8 waves/SIMD allowed; LDS 65,088B x 2 = 130KB < 160KB
// -> 2 blocks/CU = 32 waves/CU, v4-clean traffic.
// ---------------------------------------------------------------------------
#define B1BYTES  21952
#define B2OFF    21952
#define BBYTES   24128
#define STAGEOFF 24128                    // + wid*2560 : per-wave 16 rows x 40 f
#define LDSBYTES (24128 + 16*2560)        // 65,088 B

__global__ void prep(const float* __restrict__ wss0, const float* __restrict__ wvv0,
                     const float* __restrict__ wss1, const float* __restrict__ wvv1,
                     const float* __restrict__ wsv,  const float* __restrict__ wvs,
                     float* __restrict__ partials, f16* __restrict__ bpack)
{
    const int b = blockIdx.x;
    const int t = threadIdx.x;
    if (b < 4) {
        float ls = 0.f, lg = 0.f;
        for (int i = b * 256 + t; i < NPTS; i += 1024) {
            float xv  = -12.0f + 24.0f * ((float)i / 200000.0f);
            float pdf = __expf(-0.5f * xv * xv) * 0.39894228040143267794f;
            float sg  = 1.0f / (1.0f + __expf(-xv));
            float si  = xv * sg;
            float wt  = (i == 0 || i == NPTS - 1) ? 0.5f : 1.0f;
            ls = fmaf(wt * si * si, pdf, ls);
            lg = fmaf(wt * sg * sg, pdf, lg);
        }
        __shared__ float r1[256], r2[256];
        r1[t] = ls; r2[t] = lg;
        __syncthreads();
        for (int st = 128; st > 0; st >>= 1) {
            if (t < st) { r1[t] += r1[t + st]; r2[t] += r2[t + st]; }
            __syncthreads();
        }
        if (t == 0) { partials[b] = r1[0]; partials[4 + b] = r2[0]; }
    } else {
        const int gid = (b - 4) * 256 + t;
        const float CSC  = 0.05590169943749474241f;                       // 1/sqrt(320)
        const float CSC3 = 0.05590169943749474241f / 1.7320508075688772935f;
        if (gid < 10976) {                       // B1: [28][49][8]
            const int tk   = gid / 392;          // 49*8
            const int rem  = gid - tk * 392;
            const int unit = rem >> 3;
            const int j    = rem & 7;
            float val = 0.f;
            if (unit < 48) {
                const int hf  = (unit >= 24) ? 1 : 0;
                const int col = unit - 24 * hf;
                const int k   = tk * 16 + hf * 8 + j;
                if (k < 256) {
                    const int u = k >> 4, t16 = k & 15;
                    val = (col < 16) ? CSC * wss0[(u * 16 + t16) * 16 + col]
                                     : CSC * wss1[(u * 16 + t16) * 8 + (col - 16)];
                } else {
                    const int kk = k - 256;
                    const int r8 = (kk >> 3) & 7, c8 = kk & 7;
                    val = (col < 16) ? CSC3 * wvv0[(r8 * 8 + c8) * 16 + col]
                                     : CSC3 * wvv1[(r8 * 8 + c8) * 8 + (col - 16)];
                }
            }
            bpack[gid] = (f16)val;
        } else if (gid < 12064) {                // B2: [8][17][8]
            const int e    = gid - 10976;
            const int ks   = e / 136;            // 17*8
            const int rem  = e - ks * 136;
            const int unit = rem >> 3;
            const int j    = rem & 7;
            float val = 0.f;
            if (unit < 16) {
                const int hf = unit >> 3;
                const int w  = unit & 7;
                const int k  = ks * 16 + hf * 8 + j;
                const int a  = k >> 3, bb = k & 7;
                val = 0.0625f * (wsv[(a * 8 + bb) * 8 + w] + wvs[(bb * 16 + a) * 8 + w]);
            }
            bpack[gid] = (f16)val;
        }
    }
}

// ---------------------------------------------------------------------------
// Main kernel v7: v4 body, 1024-thread blocks, UNCONSTRAINED allocator.
// C-layout: col = lane&31, row = (reg&3)+8*(reg>>2)+4*(lane>>5).
// ---------------------------------------------------------------------------
__global__ __launch_bounds__(1024) void seg_main(
    const float* __restrict__ x,
    const f16* __restrict__ bpack,    // 24,128 B packed B1+B2
    const float* __restrict__ partials,
    float* __restrict__ out, int n, int nchunks)
{
    const int tid  = threadIdx.x;
    const int lane = tid & 63;
    const int wid  = tid >> 6;        // 0..15
    const int col  = lane & 31;
    const int hf   = lane >> 5;

    __shared__ float4 lds4[LDSBYTES / 16];
    {
        const float4* src = (const float4*)bpack;
#pragma unroll
        for (int i = 0; i < 2; ++i) {
            const int idx = i * 1024 + tid;
            if (idx < BBYTES / 16) lds4[idx] = src[idx];
        }
    }
    __syncthreads();

    char* ldsc = (char*)lds4;
    // per-lane B-fragment base byte offsets (zero unit for inactive lanes)
    const int uA = (col < 24) ? (hf * 24 + col) * 16 : 48 * 16;
    const int u0 = B2OFF + ((col >= 24) ? (hf * 8 + col - 24) * 16 : 256);
    const int u1 = B2OFF + ((col < 8)   ? (hf * 8 + col) * 16      : 256);
    const int u2 = B2OFF + ((col >= 8 && col < 16) ? (hf * 8 + col - 8) * 16 : 256);
    const f16x8* BA  = (const f16x8*)(ldsc + uA);   // index t*49  (784 B stride)
    const f16x8* B0p = (const f16x8*)(ldsc + u0);   // index ks*17 (272 B stride)
    const f16x8* B1p = (const f16x8*)(ldsc + u1);
    const f16x8* B2p = (const f16x8*)(ldsc + u2);

    float*  stagef = (float*)(ldsc + STAGEOFF + wid * 2560);
    float4* stage4 = (float4*)(ldsc + STAGEOFF + wid * 2560);

    // gate(z,w) lives at lane hf*32+16+w; every consumer group uses w = col&7
    const int gsrc = 4 * (hf * 32 + 16 + (col & 7));
    // v-out dword offset within a 40-float row: 16 + w*3 + i per lane group
    const int vo   = 16 + (col & 7) * 3 + ((col < 8) ? 1 : ((col < 16) ? 2 : 0));
    const bool wrV = (col < 16) || (col >= 24);

    const float dx = 24.0f / 200000.0f;
    const float silu_c = rsqrtf((partials[0] + partials[1] + partials[2] + partials[3]) * dx);
    const float sig_c  = rsqrtf((partials[4] + partials[5] + partials[6] + partials[7]) * dx);

    const long long nf40 = (long long)n * 40;
    const int stride = gridDim.x * 16;

    for (int chunk = blockIdx.x * 16 + wid; chunk < nchunks; chunk += stride) {
        const int row  = chunk * 32 + col;
        const int lrow = (row < n) ? row : (n - 1);

        // ---- load row as named float4s, convert immediately ----
        f16x2 s2[8];        // s2[a] = {s[2a], s[2a+1]}
        f16x2 vc[3][4];     // vc[i][m] = {v[2m][i], v[2m+1][i]}
        {
            const float4* p4 = (const float4*)(x + (size_t)lrow * 40);
            float4 q0 = p4[0], q1 = p4[1], q2 = p4[2], q3 = p4[3], q4 = p4[4];
            float4 q5 = p4[5], q6 = p4[6], q7 = p4[7], q8 = p4[8], q9 = p4[9];
            s2[0].x = (f16)q0.x; s2[0].y = (f16)q0.y;
            s2[1].x = (f16)q0.z; s2[1].y = (f16)q0.w;
            s2[2].x = (f16)q1.x; s2[2].y = (f16)q1.y;
            s2[3].x = (f16)q1.z; s2[3].y = (f16)q1.w;
            s2[4].x = (f16)q2.x; s2[4].y = (f16)q2.y;
            s2[5].x = (f16)q2.z; s2[5].y = (f16)q2.w;
            s2[6].x = (f16)q3.x; s2[6].y = (f16)q3.y;
            s2[7].x = (f16)q3.z; s2[7].y = (f16)q3.w;
            vc[0][0].x = (f16)q4.x; vc[0][0].y = (f16)q4.w;
            vc[1][0].x = (f16)q4.y; vc[1][0].y = (f16)q5.x;
            vc[2][0].x = (f16)q4.z; vc[2][0].y = (f16)q5.y;
            vc[0][1].x = (f16)q5.z; vc[0][1].y = (f16)q6.y;
            vc[1][1].x = (f16)q5.w; vc[1][1].y = (f16)q6.z;
            vc[2][1].x = (f16)q6.x; vc[2][1].y = (f16)q6.w;
            vc[0][2].x = (f16)q7.x; vc[0][2].y = (f16)q7.w;
            vc[1][2].x = (f16)q7.y; vc[1][2].y = (f16)q8.x;
            vc[2][2].x = (f16)q7.z; vc[2][2].y = (f16)q8.y;
            vc[0][3].x = (f16)q8.z; vc[0][3].y = (f16)q9.y;
            vc[1][3].x = (f16)q8.w; vc[1][3].y = (f16)q9.z;
            vc[2][3].x = (f16)q9.x; vc[2][3].y = (f16)q9.w;
        }

        f16x2 shp[4];
#pragma unroll
        for (int m = 0; m < 4; ++m) shp[m] = hf ? s2[4 + m] : s2[m];

        union { f16x2 h[4]; f16x8 v; } A;
        f32x16 accA, accB;
#pragma unroll
        for (int r = 0; r < 16; ++r) { accA[r] = 0.f; accB[r] = 0.f; }

        // ---- path1 ss: ksteps t=0..15 -> accA ----
#pragma unroll
        for (int t = 0; t < 16; ++t) {
            f16 sv = (t & 1) ? s2[t >> 1].y : s2[t >> 1].x;
            f16x2 su2; su2.x = sv; su2.y = sv;
#pragma unroll
            for (int m = 0; m < 4; ++m) A.h[m] = su2 * shp[m];
            accA = __builtin_amdgcn_mfma_f32_32x32x16_f16(A.v, BA[t * 49], accA, 0, 0, 0);
        }
        // ---- path1 vv: ksteps tt=0..11 -> accA ----
#pragma unroll
        for (int tt = 0; tt < 12; ++tt) {
            const int i   = tt >> 2;
            const int ttm = tt & 3;
            f16x2 pr = vc[i][ttm];
            f16 sv = hf ? pr.y : pr.x;
            f16x2 su2; su2.x = sv; su2.y = sv;
#pragma unroll
            for (int m = 0; m < 4; ++m) A.h[m] = su2 * vc[i][m];
            accA = __builtin_amdgcn_mfma_f32_32x32x16_f16(A.v, BA[(16 + tt) * 49], accA, 0, 0, 0);
        }
        // ---- path2: i0 -> accA cols 24..31; i1,i2 -> accB cols 0..15 ----
#pragma unroll
        for (int ks = 0; ks < 8; ++ks) {
            f16x2 pr = s2[ks];
            f16 sv = hf ? pr.y : pr.x;
            f16x2 su2; su2.x = sv; su2.y = sv;
            union { f16x2 h[4]; f16x8 v; } A0, A1, A2;
#pragma unroll
            for (int m = 0; m < 4; ++m) {
                A0.h[m] = su2 * vc[0][m];
                A1.h[m] = su2 * vc[1][m];
                A2.h[m] = su2 * vc[2][m];
            }
            accA = __builtin_amdgcn_mfma_f32_32x32x16_f16(A0.v, B0p[ks * 17], accA, 0, 0, 0);
            accB = __builtin_amdgcn_mfma_f32_32x32x16_f16(A1.v, B1p[ks * 17], accB, 0, 0, 0);
            accB = __builtin_amdgcn_mfma_f32_32x32x16_f16(A2.v, B2p[ks * 17], accB, 0, 0, 0);
        }

        // ---- epilogue: stage 16 rows in LDS, flush fully coalesced ----
#pragma unroll
        for (int half = 0; half < 2; ++half) {
#pragma unroll
            for (int rr = 0; rr < 8; ++rr) {
                const int r = half * 8 + rr;
                const float aval = accA[r];
                const float sgm  = 1.0f / (1.0f + __expf(-aval));
                const float gm   = __int_as_float(
                    __builtin_amdgcn_ds_bpermute(gsrc, __float_as_int(sig_c * sgm)));
                const int zloc = (rr & 3) + 8 * (rr >> 2) + 4 * hf;   // z - half*16
                if (col < 16) stagef[zloc * 40 + col] = silu_c * aval * sgm;
                if (wrV)      stagef[zloc * 40 + vo]  = gm * ((col < 16) ? accB[r] : aval);
            }
            // flush 16 rows = 2560 B, contiguous in out
            if (chunk * 32 + half * 16 + 15 < n) {
                float4* o4 = (float4*)out + (size_t)chunk * 320 + half * 160;
                float4 f0 = stage4[lane];
                float4 f1 = stage4[64 + lane];
                o4[lane]      = f0;
                o4[64 + lane] = f1;
                if (lane < 32) { float4 f2 = stage4[128 + lane]; o4[128 + lane] = f2; }
            } else {
#pragma unroll
                for (int k2 = 0; k2 < 3; ++k2) {
                    if (k2 == 2 && lane >= 32) break;
                    float4 fv = stage4[k2 * 64 + lane];
                    const long long fbase = (long long)chunk * 1280 + half * 640
                                          + (k2 * 64 + lane) * 4;
#pragma unroll
                    for (int e = 0; e < 4; ++e) {
                        const long long fi = fbase + e;
                        if (fi < nf40) out[fi] = ((const float*)&fv)[e];
                    }
                }
            }
        }
    }
}

// ---------------------------------------------------------------------------
extern "C" void kernel_launch(void* const* d_in, const int* in_sizes, int n_in,
                              void* d_out, int out_size, void* d_ws, size_t ws_size,
                              hipStream_t stream)
{
    (void)n_in; (void)out_size; (void)ws_size;
    const float* x    = (const float*)d_in[0];
    const float* wss0 = (const float*)d_in[1];
    const float* wvv0 = (const float*)d_in[2];
    const float* wss1 = (const float*)d_in[3];
    const float* wvv1 = (const float*)d_in[4];
    const float* wsv  = (const float*)d_in[5];
    const float* wvs  = (const float*)d_in[6];
    float* out = (float*)d_out;
    const int n = in_sizes[0] / 40;
    const int nchunks = (n + 31) / 32;

    char* ws = (char*)d_ws;
    float* partials = (float*)(ws + 0);        // 8 floats
    f16*   bpack    = (f16*)(ws + 1024);       // 24,128 B packed B1+B2

    int grid = (nchunks + 15) / 16;
    if (grid > 512) grid = 512;                // 2 blocks/CU resident

    hipLaunchKernelGGL(prep, dim3(52), dim3(256), 0, stream,
                       wss0, wvv0, wss1, wvv1, wsv, wvs, partials, bpack);
    hipLaunchKernelGGL(seg_main, dim3(grid), dim3(1024), 0, stream,
                       x, bpack, partials, out, n, nchunks);
}